// Round 3
// baseline (392.697 us; speedup 1.0000x reference)
//
#include <hip/hip_runtime.h>
#include <hip/hip_bf16.h>

typedef unsigned short ushort_t;
typedef __attribute__((ext_vector_type(4))) float floatx4;
typedef __attribute__((ext_vector_type(8))) short short8;

__device__ __forceinline__ float bf2f(ushort_t u) {
    union { unsigned int i; float f; } v; v.i = ((unsigned int)u) << 16; return v.f;
}
__device__ __forceinline__ ushort_t f2bf(float f) {
    union { float f; unsigned int i; } v; v.f = f;
    unsigned int i = v.i;
    i += 0x7fffu + ((i >> 16) & 1u);            // RNE
    return (ushort_t)(i >> 16);
}
__device__ __forceinline__ float fsig(float x)  { return 1.f / (1.f + __expf(-x)); }
__device__ __forceinline__ float ftanh(float x) { return 1.f - 2.f / (__expf(2.f * x) + 1.f); }

__device__ __forceinline__ floatx4 MFMA16(short8 a, short8 b, floatx4 c) {
    return __builtin_amdgcn_mfma_f32_16x16x32_bf16(a, b, c, 0, 0, 0);
}

// ---------------------------------------------------------------------------
// K0: dtype detection. Inputs bounded by |v|<0.1<2^-3, so a genuine bf16 has
// exponent field <= 0x7B. If data is f32, the LOW ushort of each word is
// random mantissa bits -> exponent field > 0x7B ~52% of the time.
// ---------------------------------------------------------------------------
__global__ __launch_bounds__(64) void detect_kernel(const unsigned int* __restrict__ raw,
                                                    int* __restrict__ flag) {
    int c = 0;
    for (int i = 0; i < 16; ++i) {
        unsigned int v = raw[threadIdx.x * 16 + i];
        unsigned int e = (v >> 7) & 0xFFu;      // low-ushort bf16 exponent field
        if (e > 0x7Bu) ++c;
    }
    c += __shfl_xor(c, 1);  c += __shfl_xor(c, 2);  c += __shfl_xor(c, 4);
    c += __shfl_xor(c, 8);  c += __shfl_xor(c, 16); c += __shfl_xor(c, 32);
    if (threadIdx.x == 0) *flag = (c > 64) ? 1 : 0;   // 1 => inputs are f32
}

// ---------------------------------------------------------------------------
// K0b: canonicalize all float inputs to bf16 in ws.
// ---------------------------------------------------------------------------
struct ConvArgs {
    const void* src[25];
    int dstoff[25];
    int count[25];
    int cumblk[26];
};

__global__ __launch_bounds__(256) void convert_kernel(ConvArgs a, ushort_t* __restrict__ dst,
                                                      const int* __restrict__ flag) {
    int b = blockIdx.x;
    int lo = 0, hi = 24;
    while (lo < hi) { int mid = (lo + hi + 1) >> 1; if (a.cumblk[mid] <= b) lo = mid; else hi = mid - 1; }
    int j = lo;
    size_t base = (size_t)(b - a.cumblk[j]) * 2048 + (size_t)threadIdx.x * 8;
    if (base >= (size_t)a.count[j]) return;
    ushort_t* out = dst + a.dstoff[j] + base;
    if (*flag) {
        const float* s = (const float*)a.src[j] + base;
        float4 v0 = *(const float4*)s;
        float4 v1 = *(const float4*)(s + 4);
        union { ushort_t u[8]; uint4 v; } o;
        o.u[0] = f2bf(v0.x); o.u[1] = f2bf(v0.y); o.u[2] = f2bf(v0.z); o.u[3] = f2bf(v0.w);
        o.u[4] = f2bf(v1.x); o.u[5] = f2bf(v1.y); o.u[6] = f2bf(v1.z); o.u[7] = f2bf(v1.w);
        *(uint4*)out = o.v;
    } else {
        *(uint4*)out = *(const uint4*)((const ushort_t*)a.src[j] + base);
    }
}

// ---------------------------------------------------------------------------
// K1: sequence lengths (word + sentence levels) and global maxima. 1 block.
// ---------------------------------------------------------------------------
__global__ __launch_bounds__(256) void lens_kernel(const int* __restrict__ x,
                                                   int* wlens, int* slens,
                                                   int* wmax, int* smax) {
    __shared__ int nzf[1024];
    __shared__ int red[256];
    int tid = threadIdx.x;
    int lmax = 0;
    for (int k = 0; k < 4; ++k) {
        int sid = k * 256 + tid;
        const int* tok = x + sid * 64;
        int last = 0;
        for (int t = 0; t < 64; t += 4) {
            int4 v = *(const int4*)(tok + t);
            if (v.x) last = t + 1;
            if (v.y) last = t + 2;
            if (v.z) last = t + 3;
            if (v.w) last = t + 4;
        }
        int any = last > 0;
        int len = any ? last : 1;
        wlens[sid] = len;
        nzf[sid] = any;
        lmax = max(lmax, len);
    }
    red[tid] = lmax;
    __syncthreads();
    for (int off = 128; off; off >>= 1) {
        if (tid < off) red[tid] = max(red[tid], red[tid + off]);
        __syncthreads();
    }
    if (tid == 0) *wmax = red[0];
    __syncthreads();
    if (tid < 32) {
        int last = 0;
        for (int s = 0; s < 32; ++s) if (nzf[tid * 32 + s]) last = s + 1;
        int len = last ? last : 1;
        slens[tid] = len;
        red[tid] = len;
    }
    __syncthreads();
    if (tid == 0) {
        int m = 0;
        for (int s = 0; s < 32; ++s) m = max(m, red[s]);
        *smax = m;
    }
}

// ---------------------------------------------------------------------------
// G: MFMA GEMM  C[M,N] = A[M,K=256] @ B[N,K]^T + bias[N]; bf16 in.
// Output bf16 normally; if flagp && *flagp, f32 to Cf (final classifier).
// ---------------------------------------------------------------------------
__global__ __launch_bounds__(256) void gemm_kernel(const ushort_t* __restrict__ A,
                                                   const ushort_t* __restrict__ B,
                                                   const ushort_t* __restrict__ bias,
                                                   ushort_t* __restrict__ C,
                                                   float* __restrict__ Cf,
                                                   const int* __restrict__ flagp,
                                                   int M, int N, int K) {
    __shared__ ushort_t As[64 * 256];
    __shared__ ushort_t Bs[64 * 256];
    int tid = threadIdx.x;
    int m0 = blockIdx.x * 64, n0 = blockIdx.y * 64;
    int KC = K >> 3;
    int total = 64 * KC;
    for (int idx = tid; idx < total; idx += 256) {
        int m = idx & 63, c = idx >> 6;
        int mm = m0 + m;
        uint4 val = {0u, 0u, 0u, 0u};
        if (mm < M) val = *(const uint4*)(A + (size_t)mm * K + c * 8);
        *(uint4*)&As[(c * 64 + m) * 8] = val;
    }
    for (int idx = tid; idx < total; idx += 256) {
        int n = idx & 63, c = idx >> 6;
        int nn = n0 + n;
        uint4 val = {0u, 0u, 0u, 0u};
        if (nn < N) val = *(const uint4*)(B + (size_t)nn * K + c * 8);
        *(uint4*)&Bs[(c * 64 + n) * 8] = val;
    }
    __syncthreads();
    int lane = tid & 63, wave = tid >> 6;
    int wm = (wave & 1) * 32, wn = (wave >> 1) * 32;
    int l15 = lane & 15, l4 = lane >> 4;
    floatx4 acc[2][2] = {};
    int KF = K >> 5;
    for (int kf = 0; kf < KF; ++kf) {
        int c = kf * 4 + l4;
        short8 a0 = *(const short8*)&As[(c * 64 + wm + l15) * 8];
        short8 a1 = *(const short8*)&As[(c * 64 + wm + 16 + l15) * 8];
        short8 b0 = *(const short8*)&Bs[(c * 64 + wn + l15) * 8];
        short8 b1 = *(const short8*)&Bs[(c * 64 + wn + 16 + l15) * 8];
        acc[0][0] = MFMA16(a0, b0, acc[0][0]);
        acc[0][1] = MFMA16(a0, b1, acc[0][1]);
        acc[1][0] = MFMA16(a1, b0, acc[1][0]);
        acc[1][1] = MFMA16(a1, b1, acc[1][1]);
    }
    int fOut = flagp ? *flagp : 0;
    for (int nt = 0; nt < 2; ++nt) {
        int n = n0 + wn + nt * 16 + l15;
        float bv = (n < N) ? bf2f(bias[n]) : 0.f;
        for (int mt = 0; mt < 2; ++mt) {
            int mbase = m0 + wm + mt * 16 + l4 * 4;
            #pragma unroll
            for (int i = 0; i < 4; ++i) {
                int m = mbase + i;
                if (m < M && n < N) {
                    float v = acc[mt][nt][i] + bv;
                    if (fOut) Cf[(size_t)m * N + n] = v;
                    else      C[(size_t)m * N + n] = f2bf(v);
                }
            }
        }
    }
}

// ---------------------------------------------------------------------------
// Fused word-level BiGRU: embedding gather + input projection + recurrence.
// grid = (64, 2); block = 512 (8 waves). Block: 16 sequences, one direction.
// ---------------------------------------------------------------------------
#define SGD 20

__global__ __launch_bounds__(512) void word_gru_kernel(
        const int* __restrict__ x, const ushort_t* __restrict__ emb,
        const ushort_t* __restrict__ Wih_f, const ushort_t* __restrict__ Whh_f,
        const ushort_t* __restrict__ bih_f, const ushort_t* __restrict__ bhh_f,
        const ushort_t* __restrict__ Wih_b, const ushort_t* __restrict__ Whh_b,
        const ushort_t* __restrict__ bih_b, const ushort_t* __restrict__ bhh_b,
        const int* __restrict__ lens, ushort_t* __restrict__ out) {
    const int T = 64;
    __shared__ ushort_t h_lds[2048];
    __shared__ ushort_t x_lds[2][2048];
    __shared__ float xg_lds[384 * SGD];
    __shared__ float hg_lds[384 * SGD];
    __shared__ float bsum_lds[256];
    __shared__ float bihn_lds[128];
    __shared__ float bhhn_lds[128];
    __shared__ int tok_lds[16 * 64];
    __shared__ int len_lds[16];

    int tid = threadIdx.x;
    int d = blockIdx.y;
    int n0 = blockIdx.x * 16;
    const ushort_t* Wih = d ? Wih_b : Wih_f;
    const ushort_t* Whh = d ? Whh_b : Whh_f;
    const ushort_t* bih = d ? bih_b : bih_f;
    const ushort_t* bhh = d ? bhh_b : bhh_f;
    int lane = tid & 63, wave = tid >> 6;
    int l15 = lane & 15, l4 = lane >> 4;

    ((int2*)tok_lds)[tid] = ((const int2*)(x + n0 * 64))[tid];
    if (tid < 256) bsum_lds[tid] = bf2f(bih[tid]) + bf2f(bhh[tid]);
    else if (tid < 384) {
        bihn_lds[tid - 256] = bf2f(bih[tid]);
        bhhn_lds[tid - 256] = bf2f(bhh[tid]);
    }
    if (tid < 16) len_lds[tid] = lens[n0 + tid];
    { uint2 z = {0u, 0u}; *(uint2*)&h_lds[tid * 4] = z; }

    short8 wf[3][4], uf[3][4];
    #pragma unroll
    for (int jj = 0; jj < 3; ++jj) {
        int g = (wave * 3 + jj) * 16 + l15;
        #pragma unroll
        for (int kf = 0; kf < 4; ++kf) {
            wf[jj][kf] = *(const short8*)(Wih + g * 128 + kf * 32 + l4 * 8);
            uf[jj][kf] = *(const short8*)(Whh + g * 128 + kf * 32 + l4 * 8);
        }
    }
    __syncthreads();

    int m_s = tid & 15, k0 = (tid >> 4) * 4;
    {
        int t0 = d ? (T - 1) : 0;
        int tok = tok_lds[m_s * 64 + t0];
        uint2 v = *(const uint2*)(emb + (size_t)tok * 128 + k0);
        *(uint2*)&x_lds[0][((k0 >> 3) * 16 + m_s) * 8 + (k0 & 7)] = v;
    }
    __syncthreads();

    int m_e = tid & 15;
    int j0 = (tid >> 4) * 4;
    float hreg[4] = {0.f, 0.f, 0.f, 0.f};

    for (int ti = 0; ti < T; ++ti) {
        int t = d ? (T - 1 - ti) : ti;
        int cur = ti & 1;
        uint2 xnext = {0u, 0u};
        bool have_next = (ti + 1) < T;
        if (have_next) {
            int tn = d ? (T - 2 - ti) : (ti + 1);
            int tok = tok_lds[m_s * 64 + tn];
            xnext = *(const uint2*)(emb + (size_t)tok * 128 + k0);
        }
        floatx4 xga[3] = {}, hga[3] = {};
        #pragma unroll
        for (int kf = 0; kf < 4; ++kf) {
            short8 xa = *(const short8*)&x_lds[cur][((kf * 4 + l4) * 16 + l15) * 8];
            short8 ha = *(const short8*)&h_lds[((kf * 4 + l4) * 16 + l15) * 8];
            xga[0] = MFMA16(xa, wf[0][kf], xga[0]);
            xga[1] = MFMA16(xa, wf[1][kf], xga[1]);
            xga[2] = MFMA16(xa, wf[2][kf], xga[2]);
            hga[0] = MFMA16(ha, uf[0][kf], hga[0]);
            hga[1] = MFMA16(ha, uf[1][kf], hga[1]);
            hga[2] = MFMA16(ha, uf[2][kf], hga[2]);
        }
        #pragma unroll
        for (int jj = 0; jj < 3; ++jj) {
            int n = (wave * 3 + jj) * 16 + l15;
            *(floatx4*)&xg_lds[n * SGD + l4 * 4] = xga[jj];
            *(floatx4*)&hg_lds[n * SGD + l4 * 4] = hga[jj];
        }
        __syncthreads();

        bool valid = t < len_lds[m_e];
        ushort_t ha4[4], oa4[4];
        #pragma unroll
        for (int jj = 0; jj < 4; ++jj) {
            int j = j0 + jj;
            float xr = xg_lds[j * SGD + m_e],         hr = hg_lds[j * SGD + m_e];
            float xz = xg_lds[(128 + j) * SGD + m_e], hz = hg_lds[(128 + j) * SGD + m_e];
            float xn = xg_lds[(256 + j) * SGD + m_e], hn = hg_lds[(256 + j) * SGD + m_e];
            float rr = fsig(xr + hr + bsum_lds[j]);
            float zz = fsig(xz + hz + bsum_lds[128 + j]);
            float nn = ftanh(xn + bihn_lds[j] + rr * (hn + bhhn_lds[j]));
            float hv = valid ? ((1.f - zz) * nn + zz * hreg[jj]) : hreg[jj];
            hreg[jj] = hv;
            ha4[jj] = f2bf(hv);
            oa4[jj] = valid ? ha4[jj] : (ushort_t)0;
        }
        size_t r = (size_t)(n0 + m_e) * T + t;
        ushort4 h4; h4.x = ha4[0]; h4.y = ha4[1]; h4.z = ha4[2]; h4.w = ha4[3];
        ushort4 o4; o4.x = oa4[0]; o4.y = oa4[1]; o4.z = oa4[2]; o4.w = oa4[3];
        *(ushort4*)&h_lds[((j0 >> 3) * 16 + m_e) * 8 + (j0 & 7)] = h4;
        *(ushort4*)(out + r * 256 + (size_t)d * 128 + j0) = o4;
        if (have_next)
            *(uint2*)&x_lds[cur ^ 1][((k0 >> 3) * 16 + m_s) * 8 + (k0 & 7)] = xnext;
        __syncthreads();
    }
}

// ---------------------------------------------------------------------------
// Sentence-level GRU recurrence (xp precomputed). grid=(nseq/16,2), block 512.
// ---------------------------------------------------------------------------
__global__ __launch_bounds__(512) void gru_kernel(const ushort_t* __restrict__ xp_f,
                                                  const ushort_t* __restrict__ xp_b,
                                                  const ushort_t* __restrict__ Whh_f,
                                                  const ushort_t* __restrict__ Whh_b,
                                                  const ushort_t* __restrict__ bhh_f,
                                                  const ushort_t* __restrict__ bhh_b,
                                                  const int* __restrict__ lens,
                                                  ushort_t* __restrict__ out, int T) {
    __shared__ ushort_t h_lds[2048];
    __shared__ float hg_lds[384 * SGD];
    __shared__ float bhh_lds[384];
    __shared__ int len_lds[16];
    int tid = threadIdx.x;
    int d = blockIdx.y;
    int n0 = blockIdx.x * 16;
    const ushort_t* xp  = d ? xp_b  : xp_f;
    const ushort_t* Whh = d ? Whh_b : Whh_f;
    const ushort_t* bhh = d ? bhh_b : bhh_f;
    int lane = tid & 63, wave = tid >> 6;
    int l15 = lane & 15, l4 = lane >> 4;

    short8 bfrag[3][4];
    #pragma unroll
    for (int jj = 0; jj < 3; ++jj) {
        int g = (wave * 3 + jj) * 16 + l15;
        #pragma unroll
        for (int kf = 0; kf < 4; ++kf)
            bfrag[jj][kf] = *(const short8*)(Whh + g * 128 + kf * 32 + l4 * 8);
    }
    { uint2 z = {0u, 0u}; *(uint2*)&h_lds[tid * 4] = z; }
    if (tid < 384) bhh_lds[tid] = bf2f(bhh[tid]);
    if (tid < 16) len_lds[tid] = lens[n0 + tid];
    __syncthreads();

    int m_e = tid & 15;
    int j0 = (tid >> 4) * 4;
    float hreg[4] = {0.f, 0.f, 0.f, 0.f};

    for (int ti = 0; ti < T; ++ti) {
        int t = d ? (T - 1 - ti) : ti;
        size_t r = (size_t)(n0 + m_e) * T + t;
        ushort4 xr4 = *(const ushort4*)(xp + r * 384 + j0);
        ushort4 xz4 = *(const ushort4*)(xp + r * 384 + 128 + j0);
        ushort4 xn4 = *(const ushort4*)(xp + r * 384 + 256 + j0);

        floatx4 acc[3] = {};
        #pragma unroll
        for (int kf = 0; kf < 4; ++kf) {
            short8 a = *(const short8*)&h_lds[((kf * 4 + l4) * 16 + l15) * 8];
            acc[0] = MFMA16(a, bfrag[0][kf], acc[0]);
            acc[1] = MFMA16(a, bfrag[1][kf], acc[1]);
            acc[2] = MFMA16(a, bfrag[2][kf], acc[2]);
        }
        #pragma unroll
        for (int jj = 0; jj < 3; ++jj) {
            int n = (wave * 3 + jj) * 16 + l15;
            *(floatx4*)&hg_lds[n * SGD + l4 * 4] = acc[jj];
        }
        __syncthreads();

        bool valid = t < len_lds[m_e];
        float xra[4] = {bf2f(xr4.x), bf2f(xr4.y), bf2f(xr4.z), bf2f(xr4.w)};
        float xza[4] = {bf2f(xz4.x), bf2f(xz4.y), bf2f(xz4.z), bf2f(xz4.w)};
        float xna[4] = {bf2f(xn4.x), bf2f(xn4.y), bf2f(xn4.z), bf2f(xn4.w)};
        ushort_t ha[4], oa[4];
        #pragma unroll
        for (int jj = 0; jj < 4; ++jj) {
            int j = j0 + jj;
            float hr = hg_lds[j * SGD + m_e] + bhh_lds[j];
            float hz = hg_lds[(128 + j) * SGD + m_e] + bhh_lds[128 + j];
            float hn = hg_lds[(256 + j) * SGD + m_e] + bhh_lds[256 + j];
            float rr = fsig(xra[jj] + hr);
            float zz = fsig(xza[jj] + hz);
            float nn = ftanh(xna[jj] + rr * hn);
            float hv = valid ? ((1.f - zz) * nn + zz * hreg[jj]) : hreg[jj];
            hreg[jj] = hv;
            ha[jj] = f2bf(hv);
            oa[jj] = valid ? ha[jj] : (ushort_t)0;
        }
        ushort4 h4; h4.x = ha[0]; h4.y = ha[1]; h4.z = ha[2]; h4.w = ha[3];
        ushort4 o4; o4.x = oa[0]; o4.y = oa[1]; o4.z = oa[2]; o4.w = oa[3];
        *(ushort4*)&h_lds[((j0 >> 3) * 16 + m_e) * 8 + (j0 & 7)] = h4;
        *(ushort4*)(out + r * 256 + (size_t)d * 128 + j0) = o4;
        __syncthreads();
    }
}

// ---------------------------------------------------------------------------
// Fused attention projection + score: per 64 A-rows, full N=128, K=256.
// scores[m] = sum_n tanh(A@W^T + b)[m,n] * ctx[n]  (f32 out)
// ---------------------------------------------------------------------------
__global__ __launch_bounds__(256) void score_kernel(const ushort_t* __restrict__ A,
                                                    const ushort_t* __restrict__ W,
                                                    const ushort_t* __restrict__ bias,
                                                    const ushort_t* __restrict__ ctx,
                                                    float* __restrict__ scores) {
    __shared__ ushort_t As[64 * 256];
    __shared__ ushort_t Bs[128 * 256];
    __shared__ float bc_lds[256];
    int tid = threadIdx.x;
    int m0 = blockIdx.x * 64;
    for (int idx = tid; idx < 2048; idx += 256) {
        int m = idx & 63, c = idx >> 6;
        *(uint4*)&As[(c * 64 + m) * 8] = *(const uint4*)(A + (size_t)(m0 + m) * 256 + c * 8);
    }
    for (int idx = tid; idx < 4096; idx += 256) {
        int n = idx & 127, c = idx >> 7;
        *(uint4*)&Bs[(c * 128 + n) * 8] = *(const uint4*)(W + (size_t)n * 256 + c * 8);
    }
    if (tid < 128) bc_lds[tid] = bf2f(bias[tid]);
    else if (tid < 256) bc_lds[tid] = bf2f(ctx[tid - 128]);
    __syncthreads();
    int lane = tid & 63, wave = tid >> 6;
    int l15 = lane & 15, l4 = lane >> 4;
    int wm = wave * 16;
    floatx4 acc[8] = {};
    for (int kf = 0; kf < 8; ++kf) {
        int c = kf * 4 + l4;
        short8 a = *(const short8*)&As[(c * 64 + wm + l15) * 8];
        #pragma unroll
        for (int j = 0; j < 8; ++j) {
            short8 b = *(const short8*)&Bs[(c * 128 + j * 16 + l15) * 8];
            acc[j] = MFMA16(a, b, acc[j]);
        }
    }
    #pragma unroll
    for (int i = 0; i < 4; ++i) {
        float s = 0.f;
        #pragma unroll
        for (int j = 0; j < 8; ++j) {
            int n = j * 16 + l15;
            s += ftanh(acc[j][i] + bc_lds[n]) * bc_lds[128 + n];
        }
        s += __shfl_xor(s, 1);
        s += __shfl_xor(s, 2);
        s += __shfl_xor(s, 4);
        s += __shfl_xor(s, 8);
        if (l15 == 0) scores[m0 + wm + l4 * 4 + i] = s;
    }
}

// ---------------------------------------------------------------------------
// Attention pool from precomputed scores. One block per group.
// ---------------------------------------------------------------------------
__global__ __launch_bounds__(256) void attn_kernel(const float* __restrict__ scores,
                                                   const ushort_t* __restrict__ src,
                                                   const int* __restrict__ maxptr,
                                                   ushort_t* __restrict__ outp, int T) {
    __shared__ float attn[64];
    int tid = threadIdx.x;
    int g = blockIdx.x;
    if (tid < 64) {
        int ml = *maxptr;
        bool v = (tid < T) && (tid < ml);
        float sc = -1e30f;
        if (v) sc = scores[(size_t)g * T + tid];
        float mx = sc;
        for (int off = 32; off; off >>= 1) mx = fmaxf(mx, __shfl_xor(mx, off));
        float e = v ? __expf(sc - mx) : 0.f;
        float sum = e;
        for (int off = 32; off; off >>= 1) sum += __shfl_xor(sum, off);
        attn[tid] = e / fmaxf(sum, 1e-30f);
    }
    __syncthreads();
    float acc = 0.f;
    const ushort_t* sp = src + (size_t)g * T * 256 + tid;
    for (int tt = 0; tt < T; ++tt) acc += attn[tt] * bf2f(sp[(size_t)tt * 256]);
    outp[(size_t)g * 256 + tid] = f2bf(acc);
}

// ---------------------------------------------------------------------------
extern "C" void kernel_launch(void* const* d_in, const int* in_sizes, int n_in,
                              void* d_out, int out_size, void* d_ws, size_t ws_size,
                              hipStream_t stream) {
    const int* x = (const int*)d_in[0];
    char* ws = (char*)d_ws;

    // ws layout (bytes), total ~51.2 MB
    const size_t O_CONV   = 0;            // canonical bf16 inputs (~13.93 MB)
    const size_t O_WOUT   = 14680064;     // [65536,256] bf16
    const size_t O_WSCORE = 48234496;     // [65536] f32
    const size_t O_SENT   = 48496640;     // [1024,256] bf16
    const size_t O_SPF    = 49020928;     // [1024,384] bf16
    const size_t O_SPB    = 49807360;     // [1024,384] bf16
    const size_t O_SOUT   = 50593792;     // [1024,256] bf16
    const size_t O_SSCORE = 51118080;     // [1024] f32
    const size_t O_DOC    = 51122176;     // [32,256] bf16
    const size_t O_LENS   = 51138560;
    const size_t O_SLEN   = 51142656;
    const size_t O_WMAX   = 51142784;
    const size_t O_SMAX   = 51142788;
    const size_t O_FLAG   = 51142792;

    ushort_t* conv   = (ushort_t*)(ws + O_CONV);
    ushort_t* wout   = (ushort_t*)(ws + O_WOUT);
    float*    wscore = (float*)(ws + O_WSCORE);
    ushort_t* sent   = (ushort_t*)(ws + O_SENT);
    ushort_t* spf    = (ushort_t*)(ws + O_SPF);
    ushort_t* spb    = (ushort_t*)(ws + O_SPB);
    ushort_t* sout   = (ushort_t*)(ws + O_SOUT);
    float*    sscore = (float*)(ws + O_SSCORE);
    ushort_t* doc    = (ushort_t*)(ws + O_DOC);
    int* wlens = (int*)(ws + O_LENS);
    int* slens = (int*)(ws + O_SLEN);
    int* wmax  = (int*)(ws + O_WMAX);
    int* smax  = (int*)(ws + O_SMAX);
    int* flag  = (int*)(ws + O_FLAG);

    // Canonicalization plan: float inputs d_in[1..25] -> bf16 at conv offsets.
    ConvArgs ca;
    ushort_t* cw[25];
    int off = 0, blk = 0;
    for (int i = 1; i <= 25; ++i) {
        int j = i - 1;
        int cnt = in_sizes[i];
        ca.src[j] = d_in[i];
        ca.dstoff[j] = off;
        ca.count[j] = cnt;
        ca.cumblk[j] = blk;
        cw[j] = conv + off;
        off += cnt;
        blk += (cnt + 2047) / 2048;
    }
    ca.cumblk[25] = blk;

    // 0) dtype detect + canonicalize
    detect_kernel<<<1, 64, 0, stream>>>((const unsigned int*)d_in[1], flag);
    convert_kernel<<<blk, 256, 0, stream>>>(ca, conv, flag);
    // 1) lengths
    lens_kernel<<<1, 256, 0, stream>>>(x, wlens, slens, wmax, smax);
    // 2) fused word BiGRU (embedding gather + input proj + recurrence)
    word_gru_kernel<<<dim3(64, 2), 512, 0, stream>>>(
        x, cw[0],
        cw[1], cw[2], cw[3], cw[4],      // wf: Wih, Whh, bih, bhh
        cw[5], cw[6], cw[7], cw[8],      // wb
        wlens, wout);
    // 3) word attention: fused proj+score, then pool -> sent
    score_kernel<<<1024, 256, 0, stream>>>(wout, cw[17], cw[18], cw[19], wscore);
    attn_kernel<<<1024, 256, 0, stream>>>(wscore, wout, wmax, sent, 64);
    // 4) sentence-level input projections
    gemm_kernel<<<dim3(16, 6), 256, 0, stream>>>(sent, cw[9],  cw[11], spf, nullptr, nullptr, 1024, 384, 256);
    gemm_kernel<<<dim3(16, 6), 256, 0, stream>>>(sent, cw[13], cw[15], spb, nullptr, nullptr, 1024, 384, 256);
    // 5) sentence BiGRU
    gru_kernel<<<dim3(2, 2), 512, 0, stream>>>(spf, spb, cw[10], cw[14], cw[12], cw[16],
                                               slens, sout, 32);
    // 6) sentence attention -> doc
    score_kernel<<<16, 256, 0, stream>>>(sout, cw[20], cw[21], cw[22], sscore);
    attn_kernel<<<32, 256, 0, stream>>>(sscore, sout, smax, doc, 32);
    // 7) classifier: f32 or bf16 output per flag
    gemm_kernel<<<dim3(1, 1), 256, 0, stream>>>(doc, cw[23], cw[24],
                                                (ushort_t*)d_out, (float*)d_out, flag,
                                                32, 8, 256);
    (void)n_in; (void)out_size; (void)ws_size;
}

// Round 4
// 363.176 us; speedup vs baseline: 1.0813x; 1.0813x over previous
//
#include <hip/hip_runtime.h>
#include <hip/hip_bf16.h>

typedef unsigned short ushort_t;
typedef __attribute__((ext_vector_type(4))) float floatx4;
typedef __attribute__((ext_vector_type(8))) short short8;

__device__ __forceinline__ float bf2f(ushort_t u) {
    union { unsigned int i; float f; } v; v.i = ((unsigned int)u) << 16; return v.f;
}
__device__ __forceinline__ ushort_t f2bf(float f) {
    union { float f; unsigned int i; } v; v.f = f;
    unsigned int i = v.i;
    i += 0x7fffu + ((i >> 16) & 1u);            // RNE
    return (ushort_t)(i >> 16);
}
__device__ __forceinline__ float fsig(float x)  { return 1.f / (1.f + __expf(-x)); }
__device__ __forceinline__ float ftanh(float x) { return 1.f - 2.f / (__expf(2.f * x) + 1.f); }

__device__ __forceinline__ floatx4 MFMA16(short8 a, short8 b, floatx4 c) {
    return __builtin_amdgcn_mfma_f32_16x16x32_bf16(a, b, c, 0, 0, 0);
}

// ---------------------------------------------------------------------------
// K0: dtype detection (+ init wmax/smax for the atomicMax in lens_kernel).
// ---------------------------------------------------------------------------
__global__ __launch_bounds__(64) void detect_kernel(const unsigned int* __restrict__ raw,
                                                    int* __restrict__ flag,
                                                    int* __restrict__ wmax,
                                                    int* __restrict__ smax) {
    int c = 0;
    for (int i = 0; i < 16; ++i) {
        unsigned int v = raw[threadIdx.x * 16 + i];
        unsigned int e = (v >> 7) & 0xFFu;      // low-ushort bf16 exponent field
        if (e > 0x7Bu) ++c;
    }
    c += __shfl_xor(c, 1);  c += __shfl_xor(c, 2);  c += __shfl_xor(c, 4);
    c += __shfl_xor(c, 8);  c += __shfl_xor(c, 16); c += __shfl_xor(c, 32);
    if (threadIdx.x == 0) {
        *flag = (c > 64) ? 1 : 0;   // 1 => inputs are f32
        *wmax = 0;
        *smax = 0;
    }
}

// ---------------------------------------------------------------------------
// K0b: canonicalize all float inputs to bf16 in ws.
// ---------------------------------------------------------------------------
struct ConvArgs {
    const void* src[25];
    int dstoff[25];
    int count[25];
    int cumblk[26];
};

__global__ __launch_bounds__(256) void convert_kernel(ConvArgs a, ushort_t* __restrict__ dst,
                                                      const int* __restrict__ flag) {
    int b = blockIdx.x;
    int lo = 0, hi = 24;
    while (lo < hi) { int mid = (lo + hi + 1) >> 1; if (a.cumblk[mid] <= b) lo = mid; else hi = mid - 1; }
    int j = lo;
    size_t base = (size_t)(b - a.cumblk[j]) * 2048 + (size_t)threadIdx.x * 8;
    if (base >= (size_t)a.count[j]) return;
    ushort_t* out = dst + a.dstoff[j] + base;
    if (*flag) {
        const float* s = (const float*)a.src[j] + base;
        float4 v0 = *(const float4*)s;
        float4 v1 = *(const float4*)(s + 4);
        union { ushort_t u[8]; uint4 v; } o;
        o.u[0] = f2bf(v0.x); o.u[1] = f2bf(v0.y); o.u[2] = f2bf(v0.z); o.u[3] = f2bf(v0.w);
        o.u[4] = f2bf(v1.x); o.u[5] = f2bf(v1.y); o.u[6] = f2bf(v1.z); o.u[7] = f2bf(v1.w);
        *(uint4*)out = o.v;
    } else {
        *(uint4*)out = *(const uint4*)((const ushort_t*)a.src[j] + base);
    }
}

// ---------------------------------------------------------------------------
// K1: lengths, parallel: one block per doc (32 blocks x 64 threads).
// ---------------------------------------------------------------------------
__global__ __launch_bounds__(64) void lens_kernel(const int* __restrict__ x,
                                                  int* wlens, int* slens,
                                                  int* wmax, int* smax) {
    int b = blockIdx.x, s = threadIdx.x;
    int last = 0;
    if (s < 32) {
        const int* tok = x + (b * 32 + s) * 64;
        for (int t = 0; t < 64; t += 4) {
            int4 v = *(const int4*)(tok + t);
            if (v.x) last = t + 1;
            if (v.y) last = t + 2;
            if (v.z) last = t + 3;
            if (v.w) last = t + 4;
        }
        wlens[b * 32 + s] = last ? last : 1;
    }
    int len = (s < 32) ? (last ? last : 1) : 0;
    int lm = len;
    for (int off = 32; off; off >>= 1) lm = max(lm, __shfl_xor(lm, off));
    unsigned long long mask = __ballot(s < 32 && last > 0);
    if (s == 0) {
        int sl = mask ? (63 - (int)__clzll(mask) + 1) : 1;
        slens[b] = sl;
        atomicMax(smax, sl);
        atomicMax(wmax, lm);
    }
}

// ---------------------------------------------------------------------------
// Word-level BiGRU v2: fused gather+proj+recurrence, in-register gates.
// grid (64, 2); 512 thr = 8 waves. Block: 16 seqs, one direction.
// MFMA(W-frag as A, x/h-frag as B): lane holds (m = lane&15, j = jt+l4*4+i).
// One barrier per step; h double-buffered in LDS (bf16 A-layout).
// ---------------------------------------------------------------------------
__global__ __launch_bounds__(512, 2) void word_gru_kernel(
        const int* __restrict__ x, const ushort_t* __restrict__ emb,
        const ushort_t* __restrict__ Wih_f, const ushort_t* __restrict__ Whh_f,
        const ushort_t* __restrict__ bih_f, const ushort_t* __restrict__ bhh_f,
        const ushort_t* __restrict__ Wih_b, const ushort_t* __restrict__ Whh_b,
        const ushort_t* __restrict__ bih_b, const ushort_t* __restrict__ bhh_b,
        const int* __restrict__ lens, ushort_t* __restrict__ out) {
    const int T = 64;
    __shared__ ushort_t h_buf[2][2048];      // [k/8][m(16)][8] bf16
    __shared__ ushort_t x_buf[2][2048];
    __shared__ float bsum_lds[256];
    __shared__ float bihn_lds[128];
    __shared__ float bhhn_lds[128];
    __shared__ int tok_lds[1024];

    int tid = threadIdx.x;
    int d = blockIdx.y;
    int n0 = blockIdx.x * 16;
    const ushort_t* Wih = d ? Wih_b : Wih_f;
    const ushort_t* Whh = d ? Whh_b : Whh_f;
    const ushort_t* bih = d ? bih_b : bih_f;
    const ushort_t* bhh = d ? bhh_b : bhh_f;
    int lane = tid & 63, wave = tid >> 6;
    int l15 = lane & 15, l4 = (lane >> 4) & 3;
    int jt = wave * 16;
    int j0 = jt + l4 * 4;

    ((int2*)tok_lds)[tid] = ((const int2*)(x + n0 * 64))[tid];
    if (tid < 256) bsum_lds[tid] = bf2f(bih[tid]) + bf2f(bhh[tid]);
    else if (tid < 384) {
        bihn_lds[tid - 256] = bf2f(bih[tid]);
        bhhn_lds[tid - 256] = bf2f(bhh[tid]);
    }
    { uint2 z = {0u, 0u}; *(uint2*)&h_buf[0][tid * 4] = z; }

    // weight A-fragments (rows = gate rows jt+l15 / 128+ / 256+), registers
    short8 wr[4], wz[4], wn[4], ur[4], uz[4], un[4];
    #pragma unroll
    for (int kf = 0; kf < 4; ++kf) {
        int col = kf * 32 + l4 * 8;
        wr[kf] = *(const short8*)(Wih + (size_t)(jt + l15) * 128 + col);
        wz[kf] = *(const short8*)(Wih + (size_t)(128 + jt + l15) * 128 + col);
        wn[kf] = *(const short8*)(Wih + (size_t)(256 + jt + l15) * 128 + col);
        ur[kf] = *(const short8*)(Whh + (size_t)(jt + l15) * 128 + col);
        uz[kf] = *(const short8*)(Whh + (size_t)(128 + jt + l15) * 128 + col);
        un[kf] = *(const short8*)(Whh + (size_t)(256 + jt + l15) * 128 + col);
    }
    __syncthreads();                         // tok_lds + biases + h zero ready

    floatx4 br  = *(floatx4*)&bsum_lds[j0];
    floatx4 bz  = *(floatx4*)&bsum_lds[128 + j0];
    floatx4 bxn = *(floatx4*)&bihn_lds[j0];
    floatx4 bhn = *(floatx4*)&bhhn_lds[j0];
    int lv = lens[n0 + l15];
    float hreg[4] = {0.f, 0.f, 0.f, 0.f};

    int m_s = tid >> 4, k0 = (tid & 15) * 8; // staging role (tid < 256)
    if (tid < 256) {
        int t0 = d ? (T - 1) : 0;
        int tok = tok_lds[m_s * 64 + t0];
        uint4 v = *(const uint4*)(emb + (size_t)tok * 128 + k0);
        *(uint4*)&x_buf[0][((k0 >> 3) * 16 + m_s) * 8] = v;
    }
    __syncthreads();

    for (int ti = 0; ti < T; ++ti) {
        int t = d ? (T - 1 - ti) : ti;
        int cur = ti & 1;
        uint4 xnext;
        bool have_next = (ti + 1) < T;
        if (tid < 256 && have_next) {
            int tn = d ? (T - 2 - ti) : (ti + 1);
            xnext = *(const uint4*)(emb + (size_t)tok_lds[m_s * 64 + tn] * 128 + k0);
        }
        floatx4 ar = br, az = bz, axn = bxn, ahn = bhn;
        #pragma unroll
        for (int kf = 0; kf < 4; ++kf) {
            short8 xb = *(const short8*)&x_buf[cur][((kf * 4 + l4) * 16 + l15) * 8];
            short8 hb = *(const short8*)&h_buf[cur][((kf * 4 + l4) * 16 + l15) * 8];
            ar  = MFMA16(wr[kf], xb, ar);
            ar  = MFMA16(ur[kf], hb, ar);
            az  = MFMA16(wz[kf], xb, az);
            az  = MFMA16(uz[kf], hb, az);
            axn = MFMA16(wn[kf], xb, axn);
            ahn = MFMA16(un[kf], hb, ahn);
        }
        bool valid = t < lv;
        ushort_t hu[4], ou[4];
        #pragma unroll
        for (int i = 0; i < 4; ++i) {
            float r  = fsig(ar[i]);
            float z  = fsig(az[i]);
            float nn = ftanh(axn[i] + r * ahn[i]);
            float hv = valid ? (nn + z * (hreg[i] - nn)) : hreg[i];
            hreg[i] = hv;
            hu[i] = f2bf(hv);
            ou[i] = valid ? hu[i] : (ushort_t)0;
        }
        ushort4 h4; h4.x = hu[0]; h4.y = hu[1]; h4.z = hu[2]; h4.w = hu[3];
        ushort4 o4; o4.x = ou[0]; o4.y = ou[1]; o4.z = ou[2]; o4.w = ou[3];
        *(ushort4*)&h_buf[cur ^ 1][((j0 >> 3) * 16 + l15) * 8 + (j0 & 7)] = h4;
        *(ushort4*)(out + ((size_t)(n0 + l15) * T + t) * 256 + d * 128 + j0) = o4;
        if (tid < 256 && have_next)
            *(uint4*)&x_buf[cur ^ 1][((k0 >> 3) * 16 + m_s) * 8] = xnext;
        __syncthreads();
    }
}

// ---------------------------------------------------------------------------
// Sentence-level GRU (h-only, xp precomputed). grid (2,2); 512 thr. T=32.
// ---------------------------------------------------------------------------
__global__ __launch_bounds__(512, 2) void sent_gru_kernel(
        const ushort_t* __restrict__ xp_f, const ushort_t* __restrict__ xp_b,
        const ushort_t* __restrict__ Whh_f, const ushort_t* __restrict__ Whh_b,
        const ushort_t* __restrict__ bhh_f, const ushort_t* __restrict__ bhh_b,
        const int* __restrict__ lens, ushort_t* __restrict__ out) {
    const int T = 32;
    __shared__ ushort_t h_buf[2][2048];
    __shared__ float bhh_lds[384];

    int tid = threadIdx.x;
    int d = blockIdx.y;
    int n0 = blockIdx.x * 16;
    const ushort_t* xp  = d ? xp_b  : xp_f;
    const ushort_t* Whh = d ? Whh_b : Whh_f;
    const ushort_t* bhh = d ? bhh_b : bhh_f;
    int lane = tid & 63, wave = tid >> 6;
    int l15 = lane & 15, l4 = (lane >> 4) & 3;
    int jt = wave * 16;
    int j0 = jt + l4 * 4;

    if (tid < 384) bhh_lds[tid] = bf2f(bhh[tid]);
    { uint2 z = {0u, 0u}; *(uint2*)&h_buf[0][tid * 4] = z; }

    short8 ur[4], uz[4], un[4];
    #pragma unroll
    for (int kf = 0; kf < 4; ++kf) {
        int col = kf * 32 + l4 * 8;
        ur[kf] = *(const short8*)(Whh + (size_t)(jt + l15) * 128 + col);
        uz[kf] = *(const short8*)(Whh + (size_t)(128 + jt + l15) * 128 + col);
        un[kf] = *(const short8*)(Whh + (size_t)(256 + jt + l15) * 128 + col);
    }
    __syncthreads();

    floatx4 br  = *(floatx4*)&bhh_lds[j0];
    floatx4 bz  = *(floatx4*)&bhh_lds[128 + j0];
    floatx4 bhn = *(floatx4*)&bhh_lds[256 + j0];
    int lv = lens[n0 + l15];
    float hreg[4] = {0.f, 0.f, 0.f, 0.f};

    for (int ti = 0; ti < T; ++ti) {
        int t = d ? (T - 1 - ti) : ti;
        int cur = ti & 1;
        size_t xrow = ((size_t)(n0 + l15) * T + t) * 384;
        ushort4 xr4 = *(const ushort4*)(xp + xrow + j0);
        ushort4 xz4 = *(const ushort4*)(xp + xrow + 128 + j0);
        ushort4 xn4 = *(const ushort4*)(xp + xrow + 256 + j0);
        floatx4 ar = br, az = bz, ahn = bhn;
        #pragma unroll
        for (int kf = 0; kf < 4; ++kf) {
            short8 hb = *(const short8*)&h_buf[cur][((kf * 4 + l4) * 16 + l15) * 8];
            ar  = MFMA16(ur[kf], hb, ar);
            az  = MFMA16(uz[kf], hb, az);
            ahn = MFMA16(un[kf], hb, ahn);
        }
        float xr[4] = {bf2f(xr4.x), bf2f(xr4.y), bf2f(xr4.z), bf2f(xr4.w)};
        float xz[4] = {bf2f(xz4.x), bf2f(xz4.y), bf2f(xz4.z), bf2f(xz4.w)};
        float xn[4] = {bf2f(xn4.x), bf2f(xn4.y), bf2f(xn4.z), bf2f(xn4.w)};
        bool valid = t < lv;
        ushort_t hu[4], ou[4];
        #pragma unroll
        for (int i = 0; i < 4; ++i) {
            float r  = fsig(xr[i] + ar[i]);
            float z  = fsig(xz[i] + az[i]);
            float nn = ftanh(xn[i] + r * ahn[i]);
            float hv = valid ? (nn + z * (hreg[i] - nn)) : hreg[i];
            hreg[i] = hv;
            hu[i] = f2bf(hv);
            ou[i] = valid ? hu[i] : (ushort_t)0;
        }
        ushort4 h4; h4.x = hu[0]; h4.y = hu[1]; h4.z = hu[2]; h4.w = hu[3];
        ushort4 o4; o4.x = ou[0]; o4.y = ou[1]; o4.z = ou[2]; o4.w = ou[3];
        *(ushort4*)&h_buf[cur ^ 1][((j0 >> 3) * 16 + l15) * 8 + (j0 & 7)] = h4;
        *(ushort4*)(out + ((size_t)(n0 + l15) * T + t) * 256 + d * 128 + j0) = o4;
        __syncthreads();
    }
}

// ---------------------------------------------------------------------------
// G2: sentence xp GEMM, both directions in one launch. grid (16, 12).
// C = A[1024,256] @ B[384,256]^T + bias  (exact tiling, no edge checks)
// ---------------------------------------------------------------------------
__global__ __launch_bounds__(256) void gemm2_kernel(const ushort_t* __restrict__ A,
                                                    const ushort_t* __restrict__ Bf_,
                                                    const ushort_t* __restrict__ biasf,
                                                    ushort_t* __restrict__ Cf_,
                                                    const ushort_t* __restrict__ Bb_,
                                                    const ushort_t* __restrict__ biasb,
                                                    ushort_t* __restrict__ Cb_) {
    __shared__ ushort_t As[64 * 256];
    __shared__ ushort_t Bs[64 * 256];
    const int K = 256, N = 384;
    int tid = threadIdx.x;
    int by = blockIdx.y;
    bool sb = by >= 6;
    int n0 = (sb ? by - 6 : by) * 64;
    const ushort_t* B = sb ? Bb_ : Bf_;
    const ushort_t* bias = sb ? biasb : biasf;
    ushort_t* C = sb ? Cb_ : Cf_;
    int m0 = blockIdx.x * 64;
    for (int idx = tid; idx < 2048; idx += 256) {
        int m = idx & 63, c = idx >> 6;
        *(uint4*)&As[(c * 64 + m) * 8] = *(const uint4*)(A + (size_t)(m0 + m) * K + c * 8);
    }
    for (int idx = tid; idx < 2048; idx += 256) {
        int n = idx & 63, c = idx >> 6;
        *(uint4*)&Bs[(c * 64 + n) * 8] = *(const uint4*)(B + (size_t)(n0 + n) * K + c * 8);
    }
    __syncthreads();
    int lane = tid & 63, wave = tid >> 6;
    int wm = (wave & 1) * 32, wn = (wave >> 1) * 32;
    int l15 = lane & 15, l4 = lane >> 4;
    floatx4 acc[2][2] = {};
    for (int kf = 0; kf < 8; ++kf) {
        int c = kf * 4 + l4;
        short8 a0 = *(const short8*)&As[(c * 64 + wm + l15) * 8];
        short8 a1 = *(const short8*)&As[(c * 64 + wm + 16 + l15) * 8];
        short8 b0 = *(const short8*)&Bs[(c * 64 + wn + l15) * 8];
        short8 b1 = *(const short8*)&Bs[(c * 64 + wn + 16 + l15) * 8];
        acc[0][0] = MFMA16(a0, b0, acc[0][0]);
        acc[0][1] = MFMA16(a0, b1, acc[0][1]);
        acc[1][0] = MFMA16(a1, b0, acc[1][0]);
        acc[1][1] = MFMA16(a1, b1, acc[1][1]);
    }
    for (int nt = 0; nt < 2; ++nt) {
        int n = n0 + wn + nt * 16 + l15;
        float bv = bf2f(bias[n]);
        for (int mt = 0; mt < 2; ++mt) {
            int mbase = m0 + wm + mt * 16 + l4 * 4;
            #pragma unroll
            for (int i = 0; i < 4; ++i)
                C[(size_t)(mbase + i) * N + n] = f2bf(acc[mt][nt][i] + bv);
        }
    }
}

// ---------------------------------------------------------------------------
// Word attention fused: proj GEMM + tanh.ctx scores + softmax + pool.
// grid 1024 (per sentence); 256 thr. Reads wout ONCE (row-major LDS tile).
// ---------------------------------------------------------------------------
#define SP 264
__global__ __launch_bounds__(256) void word_attn_kernel(const ushort_t* __restrict__ wout,
                                                        const ushort_t* __restrict__ W,
                                                        const ushort_t* __restrict__ bias,
                                                        const ushort_t* __restrict__ ctx,
                                                        const int* __restrict__ maxptr,
                                                        ushort_t* __restrict__ sent) {
    __shared__ ushort_t tile[64 * SP];
    __shared__ float bc[256];
    __shared__ float sc_lds[64];
    __shared__ float p_lds[64];
    int tid = threadIdx.x, g = blockIdx.x;
    for (int idx = tid; idx < 2048; idx += 256) {
        int row = idx >> 5, k0 = (idx & 31) * 8;
        *(uint4*)&tile[row * SP + k0] = *(const uint4*)(wout + ((size_t)g * 64 + row) * 256 + k0);
    }
    if (tid < 128) bc[tid] = bf2f(bias[tid]);
    else bc[tid] = bf2f(ctx[tid - 128]);
    __syncthreads();
    int lane = tid & 63, wave = tid >> 6;
    int l15 = lane & 15, l4 = (lane >> 4) & 3;
    short8 a[8];
    #pragma unroll
    for (int kf = 0; kf < 8; ++kf)
        a[kf] = *(const short8*)&tile[(wave * 16 + l15) * SP + kf * 32 + l4 * 8];
    floatx4 acc[8];
    #pragma unroll
    for (int nt = 0; nt < 8; ++nt) {
        floatx4 c = {0.f, 0.f, 0.f, 0.f};
        #pragma unroll
        for (int kf = 0; kf < 8; ++kf) {
            short8 b = *(const short8*)(W + (size_t)(nt * 16 + l15) * 256 + kf * 32 + l4 * 8);
            c = MFMA16(a[kf], b, c);
        }
        acc[nt] = c;
    }
    float s[4] = {0.f, 0.f, 0.f, 0.f};
    #pragma unroll
    for (int nt = 0; nt < 8; ++nt) {
        float bv = bc[nt * 16 + l15], cv = bc[128 + nt * 16 + l15];
        #pragma unroll
        for (int i = 0; i < 4; ++i)
            s[i] += ftanh(acc[nt][i] + bv) * cv;
    }
    #pragma unroll
    for (int i = 0; i < 4; ++i) {
        s[i] += __shfl_xor(s[i], 1);
        s[i] += __shfl_xor(s[i], 2);
        s[i] += __shfl_xor(s[i], 4);
        s[i] += __shfl_xor(s[i], 8);
    }
    if (l15 == 0) {
        #pragma unroll
        for (int i = 0; i < 4; ++i) sc_lds[wave * 16 + l4 * 4 + i] = s[i];
    }
    __syncthreads();
    if (tid < 64) {
        int ml = *maxptr;
        bool v = tid < ml;
        float sc = v ? sc_lds[tid] : -1e30f;
        float mx = sc;
        for (int off = 32; off; off >>= 1) mx = fmaxf(mx, __shfl_xor(mx, off));
        float e = v ? __expf(sc - mx) : 0.f;
        float sum = e;
        for (int off = 32; off; off >>= 1) sum += __shfl_xor(sum, off);
        p_lds[tid] = e / fmaxf(sum, 1e-30f);
    }
    __syncthreads();
    float acc2 = 0.f;
    for (int t = 0; t < 64; ++t) acc2 += p_lds[t] * bf2f(tile[t * SP + tid]);
    sent[(size_t)g * 256 + tid] = f2bf(acc2);
}

// ---------------------------------------------------------------------------
// Sentence attention + FC fused. grid 32 (per doc); 256 thr. Writes d_out.
// ---------------------------------------------------------------------------
__global__ __launch_bounds__(256) void sent_attn_fc_kernel(const ushort_t* __restrict__ sout,
                                                           const ushort_t* __restrict__ W,
                                                           const ushort_t* __restrict__ bias,
                                                           const ushort_t* __restrict__ ctx,
                                                           const ushort_t* __restrict__ fcW,
                                                           const ushort_t* __restrict__ fcb,
                                                           const int* __restrict__ maxptr,
                                                           const int* __restrict__ flagp,
                                                           void* __restrict__ outp) {
    __shared__ ushort_t tile[32 * SP];
    __shared__ float bc[256];
    __shared__ float sc_lds[32];
    __shared__ float p_lds[32];
    __shared__ float dv[256];
    int tid = threadIdx.x, g = blockIdx.x;
    for (int idx = tid; idx < 1024; idx += 256) {
        int row = idx >> 5, k0 = (idx & 31) * 8;
        *(uint4*)&tile[row * SP + k0] = *(const uint4*)(sout + ((size_t)g * 32 + row) * 256 + k0);
    }
    if (tid < 128) bc[tid] = bf2f(bias[tid]);
    else bc[tid] = bf2f(ctx[tid - 128]);
    __syncthreads();
    int lane = tid & 63, wave = tid >> 6;
    int l15 = lane & 15, l4 = (lane >> 4) & 3;
    if (wave < 2) {
        short8 a[8];
        #pragma unroll
        for (int kf = 0; kf < 8; ++kf)
            a[kf] = *(const short8*)&tile[(wave * 16 + l15) * SP + kf * 32 + l4 * 8];
        floatx4 acc[8];
        #pragma unroll
        for (int nt = 0; nt < 8; ++nt) {
            floatx4 c = {0.f, 0.f, 0.f, 0.f};
            #pragma unroll
            for (int kf = 0; kf < 8; ++kf) {
                short8 b = *(const short8*)(W + (size_t)(nt * 16 + l15) * 256 + kf * 32 + l4 * 8);
                c = MFMA16(a[kf], b, c);
            }
            acc[nt] = c;
        }
        float s[4] = {0.f, 0.f, 0.f, 0.f};
        #pragma unroll
        for (int nt = 0; nt < 8; ++nt) {
            float bv = bc[nt * 16 + l15], cv = bc[128 + nt * 16 + l15];
            #pragma unroll
            for (int i = 0; i < 4; ++i)
                s[i] += ftanh(acc[nt][i] + bv) * cv;
        }
        #pragma unroll
        for (int i = 0; i < 4; ++i) {
            s[i] += __shfl_xor(s[i], 1);
            s[i] += __shfl_xor(s[i], 2);
            s[i] += __shfl_xor(s[i], 4);
            s[i] += __shfl_xor(s[i], 8);
        }
        if (l15 == 0) {
            #pragma unroll
            for (int i = 0; i < 4; ++i) sc_lds[wave * 16 + l4 * 4 + i] = s[i];
        }
    }
    __syncthreads();
    if (tid < 32) {
        int ml = *maxptr;
        bool v = tid < ml;
        float sc = v ? sc_lds[tid] : -1e30f;
        float mx = sc;
        for (int off = 16; off; off >>= 1) mx = fmaxf(mx, __shfl_xor(mx, off));
        float e = v ? __expf(sc - mx) : 0.f;
        float sum = e;
        for (int off = 16; off; off >>= 1) sum += __shfl_xor(sum, off);
        p_lds[tid] = e / fmaxf(sum, 1e-30f);
    }
    __syncthreads();
    float acc2 = 0.f;
    for (int t = 0; t < 32; ++t) acc2 += p_lds[t] * bf2f(tile[t * SP + tid]);
    dv[tid] = acc2;
    __syncthreads();
    // FC: c = tid>>5 (8 classes), 32 threads reduce K=256
    int c = tid >> 5, q0 = (tid & 31) * 8;
    float partial = 0.f;
    #pragma unroll
    for (int q = 0; q < 8; ++q)
        partial += dv[q0 + q] * bf2f(fcW[(size_t)c * 256 + q0 + q]);
    for (int off = 16; off; off >>= 1) partial += __shfl_xor(partial, off);
    if ((tid & 31) == 0) {
        float v = partial + bf2f(fcb[c]);
        if (*flagp) ((float*)outp)[g * 8 + c] = v;
        else        ((ushort_t*)outp)[g * 8 + c] = f2bf(v);
    }
}

// ---------------------------------------------------------------------------
extern "C" void kernel_launch(void* const* d_in, const int* in_sizes, int n_in,
                              void* d_out, int out_size, void* d_ws, size_t ws_size,
                              hipStream_t stream) {
    const int* x = (const int*)d_in[0];
    char* ws = (char*)d_ws;

    // ws layout (bytes), ~49.6 MB total
    const size_t O_CONV = 0;            // canonical bf16 inputs (~14 MB)
    const size_t O_WOUT = 14680064;     // [65536,256] bf16  33.55 MB
    const size_t O_SENT = 48234496;     // [1024,256] bf16
    const size_t O_SPF  = 48758784;     // [1024,384] bf16
    const size_t O_SPB  = 49545216;     // [1024,384] bf16
    const size_t O_SOUT = 50331648;     // [1024,256] bf16
    const size_t O_LENS = 50855936;     // wlens [1024] int
    const size_t O_SLEN = 50860032;     // slens [32] int
    const size_t O_WMAX = 50860160;
    const size_t O_SMAX = 50860164;
    const size_t O_FLAG = 50860168;

    ushort_t* conv = (ushort_t*)(ws + O_CONV);
    ushort_t* wout = (ushort_t*)(ws + O_WOUT);
    ushort_t* sent = (ushort_t*)(ws + O_SENT);
    ushort_t* spf  = (ushort_t*)(ws + O_SPF);
    ushort_t* spb  = (ushort_t*)(ws + O_SPB);
    ushort_t* sout = (ushort_t*)(ws + O_SOUT);
    int* wlens = (int*)(ws + O_LENS);
    int* slens = (int*)(ws + O_SLEN);
    int* wmax  = (int*)(ws + O_WMAX);
    int* smax  = (int*)(ws + O_SMAX);
    int* flag  = (int*)(ws + O_FLAG);

    ConvArgs ca;
    ushort_t* cw[25];
    int off = 0, blk = 0;
    for (int i = 1; i <= 25; ++i) {
        int j = i - 1;
        int cnt = in_sizes[i];
        ca.src[j] = d_in[i];
        ca.dstoff[j] = off;
        ca.count[j] = cnt;
        ca.cumblk[j] = blk;
        cw[j] = conv + off;
        off += cnt;
        blk += (cnt + 2047) / 2048;
    }
    ca.cumblk[25] = blk;

    // 0) dtype detect (+max init) + canonicalize
    detect_kernel<<<1, 64, 0, stream>>>((const unsigned int*)d_in[1], flag, wmax, smax);
    convert_kernel<<<blk, 256, 0, stream>>>(ca, conv, flag);
    // 1) lengths (32 blocks)
    lens_kernel<<<32, 64, 0, stream>>>(x, wlens, slens, wmax, smax);
    // 2) word BiGRU (fused gather+proj+recurrence, in-register gates)
    word_gru_kernel<<<dim3(64, 2), 512, 0, stream>>>(
        x, cw[0],
        cw[1], cw[2], cw[3], cw[4],      // wf: Wih, Whh, bih, bhh
        cw[5], cw[6], cw[7], cw[8],      // wb
        wlens, wout);
    // 3) word attention fused -> sent
    word_attn_kernel<<<1024, 256, 0, stream>>>(wout, cw[17], cw[18], cw[19], wmax, sent);
    // 4) sentence xp (both dirs, one launch)
    gemm2_kernel<<<dim3(16, 12), 256, 0, stream>>>(sent, cw[9], cw[11], spf,
                                                   cw[13], cw[15], spb);
    // 5) sentence BiGRU
    sent_gru_kernel<<<dim3(2, 2), 512, 0, stream>>>(spf, spb, cw[10], cw[14],
                                                    cw[12], cw[16], slens, sout);
    // 6) sentence attention + FC -> d_out
    sent_attn_fc_kernel<<<32, 256, 0, stream>>>(sout, cw[20], cw[21], cw[22],
                                                cw[23], cw[24], smax, flag, d_out);
    (void)n_in; (void)out_size; (void)ws_size;
}

// Round 5
// 321.960 us; speedup vs baseline: 1.2197x; 1.1280x over previous
//
#include <hip/hip_runtime.h>
#include <hip/hip_bf16.h>

typedef unsigned short ushort_t;
typedef __attribute__((ext_vector_type(4))) float floatx4;
typedef __attribute__((ext_vector_type(8))) short short8;

__device__ __forceinline__ float bf2f(ushort_t u) {
    union { unsigned int i; float f; } v; v.i = ((unsigned int)u) << 16; return v.f;
}
__device__ __forceinline__ ushort_t f2bf(float f) {
    union { float f; unsigned int i; } v; v.f = f;
    unsigned int i = v.i;
    i += 0x7fffu + ((i >> 16) & 1u);            // RNE
    return (ushort_t)(i >> 16);
}
__device__ __forceinline__ float fsig(float x)  { return 1.f / (1.f + __expf(-x)); }
__device__ __forceinline__ float ftanh(float x) { return 1.f - 2.f / (__expf(2.f * x) + 1.f); }

__device__ __forceinline__ floatx4 MFMA16(short8 a, short8 b, floatx4 c) {
    return __builtin_amdgcn_mfma_f32_16x16x32_bf16(a, b, c, 0, 0, 0);
}

// Swizzled LDS index for [chunk c][seq m][8 elems] bf16 tiles: XOR m into the
// chunk row so staging ds_write_b128 spreads across all 8 bank-quads.
#define XIDX(c, m) ((((c) * 16) + ((m) ^ ((c) & 15))) * 8)

// ---------------------------------------------------------------------------
// K0: dtype detection (+ init wmax/smax for the atomicMax in lens_kernel).
// ---------------------------------------------------------------------------
__global__ __launch_bounds__(64) void detect_kernel(const unsigned int* __restrict__ raw,
                                                    int* __restrict__ flag,
                                                    int* __restrict__ wmax,
                                                    int* __restrict__ smax) {
    int c = 0;
    for (int i = 0; i < 16; ++i) {
        unsigned int v = raw[threadIdx.x * 16 + i];
        unsigned int e = (v >> 7) & 0xFFu;      // low-ushort bf16 exponent field
        if (e > 0x7Bu) ++c;
    }
    c += __shfl_xor(c, 1);  c += __shfl_xor(c, 2);  c += __shfl_xor(c, 4);
    c += __shfl_xor(c, 8);  c += __shfl_xor(c, 16); c += __shfl_xor(c, 32);
    if (threadIdx.x == 0) {
        *flag = (c > 64) ? 1 : 0;   // 1 => inputs are f32
        *wmax = 0;
        *smax = 0;
    }
}

// ---------------------------------------------------------------------------
// K0b: canonicalize all float inputs to bf16 in ws.
// ---------------------------------------------------------------------------
struct ConvArgs {
    const void* src[25];
    int dstoff[25];
    int count[25];
    int cumblk[26];
};

__global__ __launch_bounds__(256) void convert_kernel(ConvArgs a, ushort_t* __restrict__ dst,
                                                      const int* __restrict__ flag) {
    int b = blockIdx.x;
    int lo = 0, hi = 24;
    while (lo < hi) { int mid = (lo + hi + 1) >> 1; if (a.cumblk[mid] <= b) lo = mid; else hi = mid - 1; }
    int j = lo;
    size_t base = (size_t)(b - a.cumblk[j]) * 2048 + (size_t)threadIdx.x * 8;
    if (base >= (size_t)a.count[j]) return;
    ushort_t* out = dst + a.dstoff[j] + base;
    if (*flag) {
        const float* s = (const float*)a.src[j] + base;
        float4 v0 = *(const float4*)s;
        float4 v1 = *(const float4*)(s + 4);
        union { ushort_t u[8]; uint4 v; } o;
        o.u[0] = f2bf(v0.x); o.u[1] = f2bf(v0.y); o.u[2] = f2bf(v0.z); o.u[3] = f2bf(v0.w);
        o.u[4] = f2bf(v1.x); o.u[5] = f2bf(v1.y); o.u[6] = f2bf(v1.z); o.u[7] = f2bf(v1.w);
        *(uint4*)out = o.v;
    } else {
        *(uint4*)out = *(const uint4*)((const ushort_t*)a.src[j] + base);
    }
}

// ---------------------------------------------------------------------------
// K1: lengths, parallel: one block per doc (32 blocks x 64 threads).
// ---------------------------------------------------------------------------
__global__ __launch_bounds__(64) void lens_kernel(const int* __restrict__ x,
                                                  int* wlens, int* slens,
                                                  int* wmax, int* smax) {
    int b = blockIdx.x, s = threadIdx.x;
    int last = 0;
    if (s < 32) {
        const int* tok = x + (b * 32 + s) * 64;
        for (int t = 0; t < 64; t += 4) {
            int4 v = *(const int4*)(tok + t);
            if (v.x) last = t + 1;
            if (v.y) last = t + 2;
            if (v.z) last = t + 3;
            if (v.w) last = t + 4;
        }
        wlens[b * 32 + s] = last ? last : 1;
    }
    int len = (s < 32) ? (last ? last : 1) : 0;
    int lm = len;
    for (int off = 32; off; off >>= 1) lm = max(lm, __shfl_xor(lm, off));
    unsigned long long mask = __ballot(s < 32 && last > 0);
    if (s == 0) {
        int sl = mask ? (63 - (int)__clzll(mask) + 1) : 1;
        slens[b] = sl;
        atomicMax(smax, sl);
        atomicMax(wmax, lm);
    }
}

// ---------------------------------------------------------------------------
// Word-level BiGRU: fused gather+proj+recurrence, in-register gates.
// grid (64, 2); 512 thr = 8 waves. Block: 16 seqs, one direction.
// ---------------------------------------------------------------------------
__global__ __launch_bounds__(512, 2) void word_gru_kernel(
        const int* __restrict__ x, const ushort_t* __restrict__ emb,
        const ushort_t* __restrict__ Wih_f, const ushort_t* __restrict__ Whh_f,
        const ushort_t* __restrict__ bih_f, const ushort_t* __restrict__ bhh_f,
        const ushort_t* __restrict__ Wih_b, const ushort_t* __restrict__ Whh_b,
        const ushort_t* __restrict__ bih_b, const ushort_t* __restrict__ bhh_b,
        const int* __restrict__ lens, ushort_t* __restrict__ out) {
    const int T = 64;
    __shared__ ushort_t h_buf[2][2048];      // swizzled [k/8][m(16)][8] bf16
    __shared__ ushort_t x_buf[2][2048];
    __shared__ float bsum_lds[256];
    __shared__ float bihn_lds[128];
    __shared__ float bhhn_lds[128];
    __shared__ int tok_lds[1024];

    int tid = threadIdx.x;
    int d = blockIdx.y;
    int n0 = blockIdx.x * 16;
    const ushort_t* Wih = d ? Wih_b : Wih_f;
    const ushort_t* Whh = d ? Whh_b : Whh_f;
    const ushort_t* bih = d ? bih_b : bih_f;
    const ushort_t* bhh = d ? bhh_b : bhh_f;
    int lane = tid & 63, wave = tid >> 6;
    int l15 = lane & 15, l4 = (lane >> 4) & 3;
    int jt = wave * 16;
    int j0 = jt + l4 * 4;

    ((int2*)tok_lds)[tid] = ((const int2*)(x + n0 * 64))[tid];
    if (tid < 256) bsum_lds[tid] = bf2f(bih[tid]) + bf2f(bhh[tid]);
    else if (tid < 384) {
        bihn_lds[tid - 256] = bf2f(bih[tid]);
        bhhn_lds[tid - 256] = bf2f(bhh[tid]);
    }
    { uint2 z = {0u, 0u}; *(uint2*)&h_buf[0][tid * 4] = z; }

    short8 wr[4], wz[4], wn[4], ur[4], uz[4], un[4];
    #pragma unroll
    for (int kf = 0; kf < 4; ++kf) {
        int col = kf * 32 + l4 * 8;
        wr[kf] = *(const short8*)(Wih + (size_t)(jt + l15) * 128 + col);
        wz[kf] = *(const short8*)(Wih + (size_t)(128 + jt + l15) * 128 + col);
        wn[kf] = *(const short8*)(Wih + (size_t)(256 + jt + l15) * 128 + col);
        ur[kf] = *(const short8*)(Whh + (size_t)(jt + l15) * 128 + col);
        uz[kf] = *(const short8*)(Whh + (size_t)(128 + jt + l15) * 128 + col);
        un[kf] = *(const short8*)(Whh + (size_t)(256 + jt + l15) * 128 + col);
    }
    __syncthreads();                         // tok_lds + biases + h zero ready

    floatx4 br  = *(floatx4*)&bsum_lds[j0];
    floatx4 bz  = *(floatx4*)&bsum_lds[128 + j0];
    floatx4 bxn = *(floatx4*)&bihn_lds[j0];
    floatx4 bhn = *(floatx4*)&bhhn_lds[j0];
    int lv = lens[n0 + l15];
    float hreg[4] = {0.f, 0.f, 0.f, 0.f};

    int m_s = tid >> 4, c_s = tid & 15;      // staging role (tid < 256)
    if (tid < 256) {
        int t0 = d ? (T - 1) : 0;
        int tok = tok_lds[m_s * 64 + t0];
        uint4 v = *(const uint4*)(emb + (size_t)tok * 128 + c_s * 8);
        *(uint4*)&x_buf[0][XIDX(c_s, m_s)] = v;
    }
    __syncthreads();

    for (int ti = 0; ti < T; ++ti) {
        int t = d ? (T - 1 - ti) : ti;
        int cur = ti & 1;
        uint4 xnext;
        bool have_next = (ti + 1) < T;
        if (tid < 256 && have_next) {
            int tn = d ? (T - 2 - ti) : (ti + 1);
            xnext = *(const uint4*)(emb + (size_t)tok_lds[m_s * 64 + tn] * 128 + c_s * 8);
        }
        floatx4 ar = br, az = bz, axn = bxn, ahn = bhn;
        #pragma unroll
        for (int kf = 0; kf < 4; ++kf) {
            short8 xb = *(const short8*)&x_buf[cur][XIDX(kf * 4 + l4, l15)];
            short8 hb = *(const short8*)&h_buf[cur][XIDX(kf * 4 + l4, l15)];
            ar  = MFMA16(wr[kf], xb, ar);
            ar  = MFMA16(ur[kf], hb, ar);
            az  = MFMA16(wz[kf], xb, az);
            az  = MFMA16(uz[kf], hb, az);
            axn = MFMA16(wn[kf], xb, axn);
            ahn = MFMA16(un[kf], hb, ahn);
        }
        bool valid = t < lv;
        ushort_t hu[4], ou[4];
        #pragma unroll
        for (int i = 0; i < 4; ++i) {
            float r  = fsig(ar[i]);
            float z  = fsig(az[i]);
            float nn = ftanh(axn[i] + r * ahn[i]);
            float hv = valid ? (nn + z * (hreg[i] - nn)) : hreg[i];
            hreg[i] = hv;
            hu[i] = f2bf(hv);
            ou[i] = valid ? hu[i] : (ushort_t)0;
        }
        ushort4 h4; h4.x = hu[0]; h4.y = hu[1]; h4.z = hu[2]; h4.w = hu[3];
        ushort4 o4; o4.x = ou[0]; o4.y = ou[1]; o4.z = ou[2]; o4.w = ou[3];
        *(ushort4*)&h_buf[cur ^ 1][XIDX(j0 >> 3, l15) + (j0 & 7)] = h4;
        *(ushort4*)(out + ((size_t)(n0 + l15) * T + t) * 256 + d * 128 + j0) = o4;
        if (tid < 256 && have_next)
            *(uint4*)&x_buf[cur ^ 1][XIDX(c_s, m_s)] = xnext;
        __syncthreads();
    }
}

// ---------------------------------------------------------------------------
// Sentence-level BiGRU v2: fused input projection (K=256) + recurrence.
// grid (2, 2); 512 thr. 16 docs per block, one direction, T=32 steps.
// sent rows staged per step (coalesced 512B/row), prefetched 1 step ahead.
// ---------------------------------------------------------------------------
__global__ __launch_bounds__(512, 1) void sent_gru_kernel(
        const ushort_t* __restrict__ sent,
        const ushort_t* __restrict__ Wih_f, const ushort_t* __restrict__ Whh_f,
        const ushort_t* __restrict__ bih_f, const ushort_t* __restrict__ bhh_f,
        const ushort_t* __restrict__ Wih_b, const ushort_t* __restrict__ Whh_b,
        const ushort_t* __restrict__ bih_b, const ushort_t* __restrict__ bhh_b,
        const int* __restrict__ lens, ushort_t* __restrict__ out) {
    const int T = 32;
    __shared__ ushort_t h_buf[2][2048];      // swizzled [k/8][m][8]
    __shared__ ushort_t x_buf[2][4096];      // swizzled, 32 chunks (K=256)
    __shared__ float bsum_lds[256];
    __shared__ float bihn_lds[128];
    __shared__ float bhhn_lds[128];

    int tid = threadIdx.x;
    int d = blockIdx.y;
    int n0 = blockIdx.x * 16;
    const ushort_t* Wih = d ? Wih_b : Wih_f;
    const ushort_t* Whh = d ? Whh_b : Whh_f;
    const ushort_t* bih = d ? bih_b : bih_f;
    const ushort_t* bhh = d ? bhh_b : bhh_f;
    int lane = tid & 63, wave = tid >> 6;
    int l15 = lane & 15, l4 = (lane >> 4) & 3;
    int jt = wave * 16;
    int j0 = jt + l4 * 4;

    if (tid < 256) bsum_lds[tid] = bf2f(bih[tid]) + bf2f(bhh[tid]);
    else if (tid < 384) {
        bihn_lds[tid - 256] = bf2f(bih[tid]);
        bhhn_lds[tid - 256] = bf2f(bhh[tid]);
    }
    { uint2 z = {0u, 0u}; *(uint2*)&h_buf[0][tid * 4] = z; }

    // Wih: [384,256] -> 8 k-frags per gate; Whh: [384,128] -> 4 k-frags.
    short8 wr[8], wz[8], wn[8];
    #pragma unroll
    for (int kf = 0; kf < 8; ++kf) {
        int col = kf * 32 + l4 * 8;
        wr[kf] = *(const short8*)(Wih + (size_t)(jt + l15) * 256 + col);
        wz[kf] = *(const short8*)(Wih + (size_t)(128 + jt + l15) * 256 + col);
        wn[kf] = *(const short8*)(Wih + (size_t)(256 + jt + l15) * 256 + col);
    }
    short8 ur[4], uz[4], un[4];
    #pragma unroll
    for (int kf = 0; kf < 4; ++kf) {
        int col = kf * 32 + l4 * 8;
        ur[kf] = *(const short8*)(Whh + (size_t)(jt + l15) * 128 + col);
        uz[kf] = *(const short8*)(Whh + (size_t)(128 + jt + l15) * 128 + col);
        un[kf] = *(const short8*)(Whh + (size_t)(256 + jt + l15) * 128 + col);
    }
    __syncthreads();

    floatx4 br  = *(floatx4*)&bsum_lds[j0];
    floatx4 bz  = *(floatx4*)&bsum_lds[128 + j0];
    floatx4 bxn = *(floatx4*)&bihn_lds[j0];
    floatx4 bhn = *(floatx4*)&bhhn_lds[j0];
    int lv = lens[n0 + l15];
    float hreg[4] = {0.f, 0.f, 0.f, 0.f};

    int m_x = tid >> 5, c_x = tid & 31;      // staging role: all 512 threads
    {
        int t0 = d ? (T - 1) : 0;
        uint4 v = *(const uint4*)(sent + ((size_t)(n0 + m_x) * T + t0) * 256 + c_x * 8);
        *(uint4*)&x_buf[0][XIDX(c_x, m_x)] = v;
    }
    __syncthreads();

    for (int ti = 0; ti < T; ++ti) {
        int t = d ? (T - 1 - ti) : ti;
        int cur = ti & 1;
        uint4 xnext;
        bool have_next = (ti + 1) < T;
        if (have_next) {
            int tn = d ? (T - 2 - ti) : (ti + 1);
            xnext = *(const uint4*)(sent + ((size_t)(n0 + m_x) * T + tn) * 256 + c_x * 8);
        }
        floatx4 ar = br, az = bz, axn = bxn, ahn = bhn;
        #pragma unroll
        for (int kf = 0; kf < 8; ++kf) {
            short8 xb = *(const short8*)&x_buf[cur][XIDX(kf * 4 + l4, l15)];
            ar  = MFMA16(wr[kf], xb, ar);
            az  = MFMA16(wz[kf], xb, az);
            axn = MFMA16(wn[kf], xb, axn);
        }
        #pragma unroll
        for (int kf = 0; kf < 4; ++kf) {
            short8 hb = *(const short8*)&h_buf[cur][XIDX(kf * 4 + l4, l15)];
            ar  = MFMA16(ur[kf], hb, ar);
            az  = MFMA16(uz[kf], hb, az);
            ahn = MFMA16(un[kf], hb, ahn);
        }
        bool valid = t < lv;
        ushort_t hu[4], ou[4];
        #pragma unroll
        for (int i = 0; i < 4; ++i) {
            float r  = fsig(ar[i]);
            float z  = fsig(az[i]);
            float nn = ftanh(axn[i] + r * ahn[i]);
            float hv = valid ? (nn + z * (hreg[i] - nn)) : hreg[i];
            hreg[i] = hv;
            hu[i] = f2bf(hv);
            ou[i] = valid ? hu[i] : (ushort_t)0;
        }
        ushort4 h4; h4.x = hu[0]; h4.y = hu[1]; h4.z = hu[2]; h4.w = hu[3];
        ushort4 o4; o4.x = ou[0]; o4.y = ou[1]; o4.z = ou[2]; o4.w = ou[3];
        *(ushort4*)&h_buf[cur ^ 1][XIDX(j0 >> 3, l15) + (j0 & 7)] = h4;
        *(ushort4*)(out + ((size_t)(n0 + l15) * T + t) * 256 + d * 128 + j0) = o4;
        if (have_next)
            *(uint4*)&x_buf[cur ^ 1][XIDX(c_x, m_x)] = xnext;
        __syncthreads();
    }
}

// ---------------------------------------------------------------------------
// Word attention fused: proj GEMM + tanh.ctx scores + softmax + pool.
// grid 1024 (per sentence); 256 thr. Reads wout ONCE (row-major LDS tile).
// ---------------------------------------------------------------------------
#define SP 264
__global__ __launch_bounds__(256) void word_attn_kernel(const ushort_t* __restrict__ wout,
                                                        const ushort_t* __restrict__ W,
                                                        const ushort_t* __restrict__ bias,
                                                        const ushort_t* __restrict__ ctx,
                                                        const int* __restrict__ maxptr,
                                                        ushort_t* __restrict__ sent) {
    __shared__ ushort_t tile[64 * SP];
    __shared__ float bc[256];
    __shared__ float sc_lds[64];
    __shared__ float p_lds[64];
    int tid = threadIdx.x, g = blockIdx.x;
    for (int idx = tid; idx < 2048; idx += 256) {
        int row = idx >> 5, k0 = (idx & 31) * 8;
        *(uint4*)&tile[row * SP + k0] = *(const uint4*)(wout + ((size_t)g * 64 + row) * 256 + k0);
    }
    if (tid < 128) bc[tid] = bf2f(bias[tid]);
    else bc[tid] = bf2f(ctx[tid - 128]);
    __syncthreads();
    int lane = tid & 63, wave = tid >> 6;
    int l15 = lane & 15, l4 = (lane >> 4) & 3;
    short8 a[8];
    #pragma unroll
    for (int kf = 0; kf < 8; ++kf)
        a[kf] = *(const short8*)&tile[(wave * 16 + l15) * SP + kf * 32 + l4 * 8];
    floatx4 acc[8];
    #pragma unroll
    for (int nt = 0; nt < 8; ++nt) {
        floatx4 c = {0.f, 0.f, 0.f, 0.f};
        #pragma unroll
        for (int kf = 0; kf < 8; ++kf) {
            short8 b = *(const short8*)(W + (size_t)(nt * 16 + l15) * 256 + kf * 32 + l4 * 8);
            c = MFMA16(a[kf], b, c);
        }
        acc[nt] = c;
    }
    float s[4] = {0.f, 0.f, 0.f, 0.f};
    #pragma unroll
    for (int nt = 0; nt < 8; ++nt) {
        float bv = bc[nt * 16 + l15], cv = bc[128 + nt * 16 + l15];
        #pragma unroll
        for (int i = 0; i < 4; ++i)
            s[i] += ftanh(acc[nt][i] + bv) * cv;
    }
    #pragma unroll
    for (int i = 0; i < 4; ++i) {
        s[i] += __shfl_xor(s[i], 1);
        s[i] += __shfl_xor(s[i], 2);
        s[i] += __shfl_xor(s[i], 4);
        s[i] += __shfl_xor(s[i], 8);
    }
    if (l15 == 0) {
        #pragma unroll
        for (int i = 0; i < 4; ++i) sc_lds[wave * 16 + l4 * 4 + i] = s[i];
    }
    __syncthreads();
    if (tid < 64) {
        int ml = *maxptr;
        bool v = tid < ml;
        float sc = v ? sc_lds[tid] : -1e30f;
        float mx = sc;
        for (int off = 32; off; off >>= 1) mx = fmaxf(mx, __shfl_xor(mx, off));
        float e = v ? __expf(sc - mx) : 0.f;
        float sum = e;
        for (int off = 32; off; off >>= 1) sum += __shfl_xor(sum, off);
        p_lds[tid] = e / fmaxf(sum, 1e-30f);
    }
    __syncthreads();
    float acc2 = 0.f;
    for (int t = 0; t < 64; ++t) acc2 += p_lds[t] * bf2f(tile[t * SP + tid]);
    sent[(size_t)g * 256 + tid] = f2bf(acc2);
}

// ---------------------------------------------------------------------------
// Sentence attention + FC fused. grid 32 (per doc); 256 thr. Writes d_out.
// ---------------------------------------------------------------------------
__global__ __launch_bounds__(256) void sent_attn_fc_kernel(const ushort_t* __restrict__ sout,
                                                           const ushort_t* __restrict__ W,
                                                           const ushort_t* __restrict__ bias,
                                                           const ushort_t* __restrict__ ctx,
                                                           const ushort_t* __restrict__ fcW,
                                                           const ushort_t* __restrict__ fcb,
                                                           const int* __restrict__ maxptr,
                                                           const int* __restrict__ flagp,
                                                           void* __restrict__ outp) {
    __shared__ ushort_t tile[32 * SP];
    __shared__ float bc[256];
    __shared__ float sc_lds[32];
    __shared__ float p_lds[32];
    __shared__ float dv[256];
    int tid = threadIdx.x, g = blockIdx.x;
    for (int idx = tid; idx < 1024; idx += 256) {
        int row = idx >> 5, k0 = (idx & 31) * 8;
        *(uint4*)&tile[row * SP + k0] = *(const uint4*)(sout + ((size_t)g * 32 + row) * 256 + k0);
    }
    if (tid < 128) bc[tid] = bf2f(bias[tid]);
    else bc[tid] = bf2f(ctx[tid - 128]);
    __syncthreads();
    int lane = tid & 63, wave = tid >> 6;
    int l15 = lane & 15, l4 = (lane >> 4) & 3;
    if (wave < 2) {
        short8 a[8];
        #pragma unroll
        for (int kf = 0; kf < 8; ++kf)
            a[kf] = *(const short8*)&tile[(wave * 16 + l15) * SP + kf * 32 + l4 * 8];
        floatx4 acc[8];
        #pragma unroll
        for (int nt = 0; nt < 8; ++nt) {
            floatx4 c = {0.f, 0.f, 0.f, 0.f};
            #pragma unroll
            for (int kf = 0; kf < 8; ++kf) {
                short8 b = *(const short8*)(W + (size_t)(nt * 16 + l15) * 256 + kf * 32 + l4 * 8);
                c = MFMA16(a[kf], b, c);
            }
            acc[nt] = c;
        }
        float s[4] = {0.f, 0.f, 0.f, 0.f};
        #pragma unroll
        for (int nt = 0; nt < 8; ++nt) {
            float bv = bc[nt * 16 + l15], cv = bc[128 + nt * 16 + l15];
            #pragma unroll
            for (int i = 0; i < 4; ++i)
                s[i] += ftanh(acc[nt][i] + bv) * cv;
        }
        #pragma unroll
        for (int i = 0; i < 4; ++i) {
            s[i] += __shfl_xor(s[i], 1);
            s[i] += __shfl_xor(s[i], 2);
            s[i] += __shfl_xor(s[i], 4);
            s[i] += __shfl_xor(s[i], 8);
        }
        if (l15 == 0) {
            #pragma unroll
            for (int i = 0; i < 4; ++i) sc_lds[wave * 16 + l4 * 4 + i] = s[i];
        }
    }
    __syncthreads();
    if (tid < 32) {
        int ml = *maxptr;
        bool v = tid < ml;
        float sc = v ? sc_lds[tid] : -1e30f;
        float mx = sc;
        for (int off = 16; off; off >>= 1) mx = fmaxf(mx, __shfl_xor(mx, off));
        float e = v ? __expf(sc - mx) : 0.f;
        float sum = e;
        for (int off = 16; off; off >>= 1) sum += __shfl_xor(sum, off);
        p_lds[tid] = e / fmaxf(sum, 1e-30f);
    }
    __syncthreads();
    float acc2 = 0.f;
    for (int t = 0; t < 32; ++t) acc2 += p_lds[t] * bf2f(tile[t * SP + tid]);
    dv[tid] = acc2;
    __syncthreads();
    // FC: c = tid>>5 (8 classes), 32 threads reduce K=256
    int c = tid >> 5, q0 = (tid & 31) * 8;
    float partial = 0.f;
    #pragma unroll
    for (int q = 0; q < 8; ++q)
        partial += dv[q0 + q] * bf2f(fcW[(size_t)c * 256 + q0 + q]);
    for (int off = 16; off; off >>= 1) partial += __shfl_xor(partial, off);
    if ((tid & 31) == 0) {
        float v = partial + bf2f(fcb[c]);
        if (*flagp) ((float*)outp)[g * 8 + c] = v;
        else        ((ushort_t*)outp)[g * 8 + c] = f2bf(v);
    }
}

// ---------------------------------------------------------------------------
extern "C" void kernel_launch(void* const* d_in, const int* in_sizes, int n_in,
                              void* d_out, int out_size, void* d_ws, size_t ws_size,
                              hipStream_t stream) {
    const int* x = (const int*)d_in[0];
    char* ws = (char*)d_ws;

    // ws layout (bytes), ~49 MB total
    const size_t O_CONV = 0;            // canonical bf16 inputs (~14 MB)
    const size_t O_WOUT = 14680064;     // [65536,256] bf16  33.55 MB
    const size_t O_SENT = 48234496;     // [1024,256] bf16
    const size_t O_SOUT = 48758784;     // [1024,256] bf16
    const size_t O_LENS = 49283072;     // wlens [1024] int
    const size_t O_SLEN = 49287168;     // slens [32] int
    const size_t O_WMAX = 49287296;
    const size_t O_SMAX = 49287300;
    const size_t O_FLAG = 49287304;

    ushort_t* conv = (ushort_t*)(ws + O_CONV);
    ushort_t* wout = (ushort_t*)(ws + O_WOUT);
    ushort_t* sent = (ushort_t*)(ws + O_SENT);
    ushort_t* sout = (ushort_t*)(ws + O_SOUT);
    int* wlens = (int*)(ws + O_LENS);
    int* slens = (int*)(ws + O_SLEN);
    int* wmax  = (int*)(ws + O_WMAX);
    int* smax  = (int*)(ws + O_SMAX);
    int* flag  = (int*)(ws + O_FLAG);

    ConvArgs ca;
    ushort_t* cw[25];
    int off = 0, blk = 0;
    for (int i = 1; i <= 25; ++i) {
        int j = i - 1;
        int cnt = in_sizes[i];
        ca.src[j] = d_in[i];
        ca.dstoff[j] = off;
        ca.count[j] = cnt;
        ca.cumblk[j] = blk;
        cw[j] = conv + off;
        off += cnt;
        blk += (cnt + 2047) / 2048;
    }
    ca.cumblk[25] = blk;

    // 0) dtype detect (+max init) + canonicalize
    detect_kernel<<<1, 64, 0, stream>>>((const unsigned int*)d_in[1], flag, wmax, smax);
    convert_kernel<<<blk, 256, 0, stream>>>(ca, conv, flag);
    // 1) lengths (32 blocks)
    lens_kernel<<<32, 64, 0, stream>>>(x, wlens, slens, wmax, smax);
    // 2) word BiGRU (fused gather+proj+recurrence, in-register gates)
    word_gru_kernel<<<dim3(64, 2), 512, 0, stream>>>(
        x, cw[0],
        cw[1], cw[2], cw[3], cw[4],      // wf: Wih, Whh, bih, bhh
        cw[5], cw[6], cw[7], cw[8],      // wb
        wlens, wout);
    // 3) word attention fused -> sent
    word_attn_kernel<<<1024, 256, 0, stream>>>(wout, cw[17], cw[18], cw[19], wmax, sent);
    // 4) sentence BiGRU (fused input projection + recurrence)
    sent_gru_kernel<<<dim3(2, 2), 512, 0, stream>>>(
        sent,
        cw[9], cw[10], cw[11], cw[12],   // sf: Wih, Whh, bih, bhh
        cw[13], cw[14], cw[15], cw[16],  // sb
        slens, sout);
    // 5) sentence attention + FC -> d_out
    sent_attn_fc_kernel<<<32, 256, 0, stream>>>(sout, cw[20], cw[21], cw[22],
                                                cw[23], cw[24], smax, flag, d_out);
    (void)n_in; (void)out_size; (void)ws_size;
}